// Round 1
// baseline (42.202 us; speedup 1.0000x reference)
//
#include <hip/hip_runtime.h>

#define NUM_CLASSES 80
#define CH 85            // channels per anchor in add_sigmoid
#define BATCH 16

// One scalar loss over B*P anchors.
// total = sum_{b,p}[ (fore+back)*bce(conf) + fore*cls_bce_sum + fore*scale*0.5*sum((loc_t-loc_p)^2) ] / BATCH
__global__ void __launch_bounds__(256)
multibox_loss_kernel(const float* __restrict__ add_sigmoid,
                     const float* __restrict__ loc_t,
                     const float* __restrict__ conf_t,
                     const float* __restrict__ scale_t,
                     const int*   __restrict__ cls_t,
                     const unsigned char* __restrict__ fore_m,
                     const unsigned char* __restrict__ back_m,
                     float* __restrict__ out,
                     int n)
{
    // --- mask dtype detection: numpy bool (1B/elem) vs int32 (4B/elem). ---
    // back = !fore elementwise. If u8 storage, bytes 1..3 are elements 1..3 and
    // fore^back == 1 there. If int32 storage, bytes 1..3 are the high bytes of
    // element 0 and are 0 in both buffers.
    const bool is_u8 =
        (((fore_m[1] ^ back_m[1]) | (fore_m[2] ^ back_m[2]) | (fore_m[3] ^ back_m[3])) & 1) != 0;
    const int* fore_i32 = (const int*)fore_m;
    const int* back_i32 = (const int*)back_m;

    float acc = 0.f;
    for (int i = blockIdx.x * blockDim.x + threadIdx.x; i < n;
         i += gridDim.x * blockDim.x) {
        float fore, back;
        if (is_u8) {
            fore = fore_m[i] ? 1.f : 0.f;
            back = back_m[i] ? 1.f : 0.f;
        } else {
            fore = fore_i32[i] ? 1.f : 0.f;
            back = back_i32[i] ? 1.f : 0.f;
        }

        const float* base = add_sigmoid + (size_t)i * CH;

        // conf BCE — needed for every anchor (fore+back == 1, but use masks faithfully)
        float cp = base[4];
        float t  = conf_t[i];
        float bce = -(t * __logf(cp) + (1.f - t) * __logf(1.f - cp));
        acc += (fore + back) * bce;

        if (fore != 0.f) {
            // --- class BCE: sum_c -log(1-p_c), corrected at the target class ---
            int k = cls_t[i];
            float s = 0.f;
            #pragma unroll 5
            for (int c = 0; c < NUM_CLASSES; ++c) {
                s -= __logf(1.f - base[5 + c]);
            }
            float pk = base[5 + k];
            s += __logf(1.f - pk) - __logf(pk);

            // --- localization: scale * 0.5 * sum((loc_t - loc_pred)^2) ---
            float w  = scale_t[i] * 0.5f;
            float d0 = loc_t[4 * (size_t)i + 0] - base[0];
            float d1 = loc_t[4 * (size_t)i + 1] - base[1];
            float d2 = loc_t[4 * (size_t)i + 2] - base[2];
            float d3 = loc_t[4 * (size_t)i + 3] - base[3];

            acc += s + w * (d0 * d0 + d1 * d1 + d2 * d2 + d3 * d3);
        }
    }

    // --- block reduction: wave64 shuffle, then LDS across waves ---
    #pragma unroll
    for (int off = 32; off > 0; off >>= 1)
        acc += __shfl_down(acc, off, 64);

    __shared__ float wsum[4];  // 256 threads = 4 waves
    int lane = threadIdx.x & 63;
    int wid  = threadIdx.x >> 6;
    if (lane == 0) wsum[wid] = acc;
    __syncthreads();
    if (threadIdx.x == 0) {
        float s = wsum[0] + wsum[1] + wsum[2] + wsum[3];
        atomicAdd(out, s * (1.f / BATCH));
    }
}

extern "C" void kernel_launch(void* const* d_in, const int* in_sizes, int n_in,
                              void* d_out, int out_size, void* d_ws, size_t ws_size,
                              hipStream_t stream) {
    const float* add_sigmoid = (const float*)d_in[0];
    const float* loc_t       = (const float*)d_in[1];
    const float* conf_t      = (const float*)d_in[2];
    const float* scale_t     = (const float*)d_in[3];
    const int*   cls_t       = (const int*)d_in[4];
    const unsigned char* fore_m = (const unsigned char*)d_in[5];
    const unsigned char* back_m = (const unsigned char*)d_in[6];
    float* out = (float*)d_out;

    const int n = in_sizes[2];  // conf_t element count = B*P

    hipMemsetAsync(out, 0, sizeof(float) * out_size, stream);

    const int block = 256;
    const int grid  = (n + block - 1) / block;
    multibox_loss_kernel<<<grid, block, 0, stream>>>(
        add_sigmoid, loc_t, conf_t, scale_t, cls_t, fore_m, back_m, out, n);
}